// Round 16
// baseline (264.685 us; speedup 1.0000x reference)
//
#include <hip/hip_runtime.h>

#define N_NODES 50000
#define IN_DIM  512
#define OUT_DIM 128
#define BN_EPS  1e-5f
#define NODES_PER_XCD 6250   // 50000 / 8

typedef __attribute__((ext_vector_type(8))) short short8;
typedef __attribute__((ext_vector_type(4))) float f32x4;

__device__ __forceinline__ unsigned short bf16_rne(float x) {
    unsigned u = __float_as_uint(x);
    unsigned r = (u + 0x7FFFu + ((u >> 16) & 1u)) >> 16;
    return (unsigned short)r;
}
__device__ __forceinline__ float bf16_to_f(unsigned short s) {
    return __uint_as_float(((unsigned)s) << 16);
}

// global -> LDS direct staging, 16B per lane. lds dest is wave-uniform;
// HW adds lane*16.
__device__ __forceinline__ void gload16(const void* g, void* l) {
    __builtin_amdgcn_global_load_lds(
        (const __attribute__((address_space(1))) void*)g,
        (__attribute__((address_space(3))) void*)l, 16, 0, 0);
}

// ---------------- CSR build ----------------

__device__ __forceinline__ int edge_is64(const int* ei) {
    return (ei[1] | ei[3] | ei[5] | ei[7]) == 0;
}

// Pack edges to uint32 (dst<<16 | src; both < 65536) + W convert/transpose.
// The 3.2MB packed array is L3-resident for the 8x partitioned re-reads in
// deg/fill, replacing ~58MB of HBM edge re-reads.
__global__ __launch_bounds__(256) void pack_wconv(
        const int* __restrict__ ei, unsigned* __restrict__ packed, int E,
        const float* __restrict__ W1, short* __restrict__ Wt1,
        const float* __restrict__ W2, short* __restrict__ Wt2,
        const float* __restrict__ W3, short* __restrict__ Wt3) {
    const int packBlocks = (E + 2047) / 2048;
    const int b = blockIdx.x;
    __shared__ short tile[64][130];
    if (b < packBlocks) {
        const int base = b * 2048;
        const int is64 = edge_is64(ei);
#pragma unroll
        for (int j = 0; j < 8; ++j) {
            int e = base + j * 256 + threadIdx.x;
            if (e < E) {
                int src, dst;
                if (is64) { src = ((const int2*)ei)[e].x; dst = ((const int2*)ei)[E + e].x; }
                else      { src = ei[e];                  dst = ei[E + e]; }
                packed[e] = ((unsigned)dst << 16) | (unsigned)src;
            }
        }
    } else {
        const int wb = b - packBlocks;   // 0..11
        const float* W; short* Wt; int K, k0;
        if (wb < 8)       { W = W1; Wt = Wt1; K = IN_DIM;  k0 = wb * 64; }
        else if (wb < 10) { W = W2; Wt = Wt2; K = OUT_DIM; k0 = (wb - 8) * 64; }
        else              { W = W3; Wt = Wt3; K = OUT_DIM; k0 = (wb - 10) * 64; }
        for (int i = threadIdx.x; i < 64 * 128; i += 256) {
            int k = i >> 7, c = i & 127;
            tile[k][c] = (short)bf16_rne(W[(size_t)(k0 + k) * 128 + c]);
        }
        __syncthreads();
        for (int i = threadIdx.x; i < 64 * 128; i += 256) {
            int c = i >> 6, k = i & 63;
            Wt[(size_t)c * K + k0 + k] = tile[k][c];
        }
    }
}

// XCD-partitioned degree count over the packed edge array (cnt lines are
// single-XCD-owned -> no cross-XCD atomic line ping-pong).
__global__ __launch_bounds__(256) void deg_kernel(
        const unsigned* __restrict__ packed, int* __restrict__ cnt, int E) {
    const int lo = (blockIdx.x & 7) * NODES_PER_XCD;
    const int hi = lo + NODES_PER_XCD;
    const int base = (blockIdx.x >> 3) * 2048;
#pragma unroll
    for (int j = 0; j < 8; ++j) {
        int e = base + j * 256 + threadIdx.x;
        if (e < E) {
            int dst = (int)(packed[e] >> 16);
            if (dst >= lo && dst < hi) atomicAdd(&cnt[dst], 1);
        }
    }
}

// ---- 3-phase multi-block exclusive scan (deg+1 per node); final phase also
// writes dinv, self-loop entry, and fill cursor ----

__global__ __launch_bounds__(1024) void scan_partial(const int* __restrict__ cnt,
                                                     int* __restrict__ psum, int n) {
    __shared__ int wsum[16];
    const int i = blockIdx.x * 1024 + threadIdx.x;
    const int lane = threadIdx.x & 63;
    const int wv = threadIdx.x >> 6;
    int v = (i < n) ? cnt[i] + 1 : 0;
#pragma unroll
    for (int d = 1; d < 64; d <<= 1) v += __shfl_xor(v, d);
    if (lane == 0) wsum[wv] = v;
    __syncthreads();
    if (threadIdx.x == 0) {
        int t = 0;
#pragma unroll
        for (int w = 0; w < 16; ++w) t += wsum[w];
        psum[blockIdx.x] = t;
    }
}

__global__ void scan_base(const int* __restrict__ psum, int* __restrict__ pbase,
                          int* __restrict__ rowp, int nb, int n) {
    const int lane = threadIdx.x;   // 64
    int orig = (lane < nb) ? psum[lane] : 0;
    int v = orig;
#pragma unroll
    for (int d = 1; d < 64; d <<= 1) {
        int t = __shfl_up(v, d);
        if (lane >= d) v += t;
    }
    if (lane < nb) pbase[lane] = v - orig;
    if (lane == nb - 1) rowp[n] = v;
}

__global__ __launch_bounds__(1024) void scan_final(int* __restrict__ cnt,
                                                   const int* __restrict__ pbase,
                                                   int* __restrict__ rowp,
                                                   float* __restrict__ dinv,
                                                   unsigned short* __restrict__ col, int n) {
    __shared__ int wsum[16];
    const int i = blockIdx.x * 1024 + threadIdx.x;
    const int lane = threadIdx.x & 63;
    const int wv = threadIdx.x >> 6;
    int orig = (i < n) ? cnt[i] + 1 : 0;    // degree incl self-loop
    int v = orig;
#pragma unroll
    for (int d = 1; d < 64; d <<= 1) {
        int t = __shfl_up(v, d);
        if (lane >= d) v += t;
    }
    if (lane == 63) wsum[wv] = v;
    __syncthreads();
    int woff = 0;
    for (int w = 0; w < wv; ++w) woff += wsum[w];
    if (i < n) {
        int rp = pbase[blockIdx.x] + woff + v - orig;
        rowp[i] = rp;
        dinv[i] = rsqrtf(fmaxf((float)orig, 1.f));
        col[rp] = (unsigned short)i;   // self loop first
        cnt[i] = rp + 1;               // cursor for edge fill
    }
}

// ---------------- MFMA GEMM body (device fn; bid = tile index) ----------------
// m97 structure: global_load_lds staged, single buffer, XOR-swizzled.
// XFORM: fused BN finalize (8 replicas) + BN+PReLU on A fragments.
// Epilogue: *dinv[row], LDS transpose, coalesced bf16 stores.

template <typename TA, int K, bool XFORM>
__device__ __forceinline__ void gemm_body(
        int bid, const TA* __restrict__ A, const short* __restrict__ Wt,
        unsigned short* __restrict__ out, int M,
        const float* __restrict__ stats, const float* __restrict__ gam,
        const float* __restrict__ bet, const float* __restrict__ alpha_p,
        const float* __restrict__ dinv) {
    constexpr int BK = 64;
    constexpr int NSTEP = K / BK;
    constexpr int UPRA = (BK * (int)sizeof(TA)) / 16;   // 16B units per A row
    constexpr int AINST = 64 * UPRA / 256;              // 4 (fp32) or 2 (bf16)
    __shared__ TA    ldsA[64 * BK];
    __shared__ short ldsB[128 * BK];
    __shared__ float bnp[256];

    const int tid  = threadIdx.x;
    const int lane = tid & 63;
    const int wv   = tid >> 6;
    const int r16  = lane & 15;
    const int g    = lane >> 4;
    const int row0 = bid * 64;
    const int arow_t = wv * 16 + r16;

    float alpha = 0.f;
    if constexpr (XFORM) {
        alpha = alpha_p[0];
        if (tid < 128) {
            float sum = 0.f, sq = 0.f;
#pragma unroll
            for (int r = 0; r < 8; ++r) {
                sum += stats[r * 256 + tid];
                sq  += stats[r * 256 + 128 + tid];
            }
            const float inv_n = 1.0f / (float)N_NODES;
            float mean = sum * inv_n;
            float var = fmaxf(sq * inv_n - mean * mean, 0.f);
            float sc = gam[tid] * rsqrtf(var + BN_EPS);
            bnp[tid] = sc;
            bnp[128 + tid] = bet[tid] - mean * sc;
        }
        __syncthreads();
    }

    f32x4 acc[8];
#pragma unroll
    for (int nf = 0; nf < 8; nf++) acc[nf] = (f32x4)(0.f);

    for (int s = 0; s < NSTEP; ++s) {
        const int k0 = s * BK;
        if (s) __syncthreads();
#pragma unroll
        for (int i = 0; i < AINST; ++i) {
            const int d   = i * 256 + tid;
            const int row = d / UPRA, p = d % UPRA;
            int grow = row0 + row; if (grow >= M) grow = M - 1;
            const char* src = (const char*)(A + (size_t)grow * K + k0) + ((p ^ (row & 7)) * 16);
            gload16(src, (char*)ldsA + (size_t)(i * 256 + wv * 64) * 16);
        }
#pragma unroll
        for (int i = 0; i < 4; ++i) {
            const int d    = i * 256 + tid;
            const int colb = d >> 3, p = d & 7;
            const short* src = Wt + (size_t)colb * K + k0 + (p ^ (colb & 7)) * 8;
            gload16(src, (char*)ldsB + (size_t)(i * 256 + wv * 64) * 16);
        }
        __syncthreads();
#pragma unroll
        for (int ksub = 0; ksub < 2; ++ksub) {
            short8 af;
            if constexpr (sizeof(TA) == 4) {
                const int q0 = ksub * 8 + g * 2;
                const float4* A4 = (const float4*)ldsA;
                float4 alo = A4[arow_t * UPRA + (q0 ^ (r16 & 7))];
                float4 ahi = A4[arow_t * UPRA + ((q0 + 1) ^ (r16 & 7))];
                float av[8] = {alo.x, alo.y, alo.z, alo.w, ahi.x, ahi.y, ahi.z, ahi.w};
#pragma unroll
                for (int j = 0; j < 8; j++) af[j] = (short)bf16_rne(av[j]);
            } else {
                short8 raw = ((const short8*)ldsA)[arow_t * 8 + ((ksub * 4 + g) ^ (r16 & 7))];
                if constexpr (XFORM) {
                    const int kb = k0 + ksub * 32 + g * 8;
#pragma unroll
                    for (int j = 0; j < 8; j++) {
                        float v = fmaf(bf16_to_f((unsigned short)raw[j]), bnp[kb + j], bnp[128 + kb + j]);
                        v = v >= 0.f ? v : alpha * v;
                        af[j] = (short)bf16_rne(v);
                    }
                } else {
                    af = raw;
                }
            }
#pragma unroll
            for (int nf = 0; nf < 8; nf++) {
                const int colb = nf * 16 + r16;
                short8 bf = ((const short8*)ldsB)[colb * 8 + ((ksub * 4 + g) ^ (r16 & 7))];
                acc[nf] = __builtin_amdgcn_mfma_f32_16x16x32_bf16(af, bf, acc[nf], 0, 0, 0);
            }
        }
    }

    // epilogue: acc -> LDS (bf16, reuse ldsB) -> coalesced stores
    __syncthreads();
    unsigned short* ot = (unsigned short*)ldsB;
#pragma unroll
    for (int r = 0; r < 4; ++r) {
        const int trow = wv * 16 + g * 4 + r;
        const int grow = row0 + trow;
        const float dv = (grow < M) ? dinv[grow] : 0.f;
#pragma unroll
        for (int nf = 0; nf < 8; nf++)
            ot[trow * 128 + nf * 16 + r16] = bf16_rne(acc[nf][r] * dv);
    }
    __syncthreads();
    {
        const int trow = wv * 16 + r16;
        const int seg  = g;
        const int grow = row0 + trow;
        if (grow < M) {
            const float4* lsrc = (const float4*)ot + trow * 16 + seg * 4;
            float4* gdst = (float4*)((char*)out + (size_t)grow * 256) + seg * 4;
#pragma unroll
            for (int i = 0; i < 4; ++i) gdst[i] = lsrc[i];
        }
    }
}

// ---------------- fused GEMM1 + XCD-partitioned CSR fill (packed reads) ----
// Blocks [0, gblocks): layer-1 GEMM. Blocks [gblocks, ...): edge fill from
// the 3.2MB packed array (L3-resident re-reads); each dst-range is written
// by one XCD only -> col/cnt lines single-XCD-owned. Fill latency hides
// under the GEMM stream (R12: fused 78us < 30+59 serial).

__global__ __launch_bounds__(256) void gemm1_fill(
        const float* __restrict__ A, const short* __restrict__ Wt,
        unsigned short* __restrict__ out, int M, const float* __restrict__ dinv,
        const unsigned* __restrict__ packed, int* __restrict__ cnt,
        unsigned short* __restrict__ col, int E, int gblocks) {
    if ((int)blockIdx.x < gblocks) {
        gemm_body<float, IN_DIM, false>(blockIdx.x, A, Wt, out, M,
                                        nullptr, nullptr, nullptr, nullptr, dinv);
    } else {
        const int fb = blockIdx.x - gblocks;
        const int lo = (fb & 7) * NODES_PER_XCD;
        const int hi = lo + NODES_PER_XCD;
        const int base = (fb >> 3) * 2048;
#pragma unroll
        for (int j = 0; j < 8; ++j) {
            int e = base + j * 256 + threadIdx.x;
            if (e < E) {
                unsigned p = packed[e];
                int dst = (int)(p >> 16);
                if (dst >= lo && dst < hi) {
                    int pos = atomicAdd(&cnt[dst], 1);
                    col[pos] = (unsigned short)(p & 0xFFFFu);
                }
            }
        }
    }
}

template <typename TA, int K, bool XFORM>
__global__ __launch_bounds__(256) void mfma_gemm(
        const TA* __restrict__ A, const short* __restrict__ Wt,
        unsigned short* __restrict__ out, int M,
        const float* __restrict__ stats, const float* __restrict__ gam,
        const float* __restrict__ bet, const float* __restrict__ alpha_p,
        const float* __restrict__ dinv) {
    gemm_body<TA, K, XFORM>(blockIdx.x, A, Wt, out, M, stats, gam, bet, alpha_p, dinv);
}

// ---------------- Aggregation + fused BN stats ----------------

template <int FINAL>
__global__ __launch_bounds__(256) void agg_kernel(
        const unsigned short* __restrict__ h, const int* __restrict__ rowp,
        const unsigned short* __restrict__ col, const float* __restrict__ dinv,
        const float* __restrict__ bias, void* __restrict__ outv,
        float* __restrict__ stats, int n) {
    const int wave = threadIdx.x >> 6;
    const int lane = threadIdx.x & 63;
    const int f = lane << 1;
    const float b0 = bias[f], b1 = bias[f + 1];
    float s0 = 0.f, s1 = 0.f, q0 = 0.f, q1 = 0.f;
    const int stride = gridDim.x << 2;
    for (int node = (blockIdx.x << 2) + wave; node < n; node += stride) {
        int e = rowp[node];
        const int end = rowp[node + 1];
        float a0 = 0.f, a1 = 0.f;
        for (; e + 8 <= end; e += 8) {
            int c[8];
#pragma unroll
            for (int j = 0; j < 8; j++) c[j] = col[e + j];
            unsigned v[8];
#pragma unroll
            for (int j = 0; j < 8; j++) v[j] = *(const unsigned*)(h + (size_t)c[j] * OUT_DIM + f);
#pragma unroll
            for (int j = 0; j < 8; j++) {
                a0 += __uint_as_float(v[j] << 16);
                a1 += __uint_as_float(v[j] & 0xFFFF0000u);
            }
        }
        for (; e < end; ++e) {
            unsigned v = *(const unsigned*)(h + (size_t)col[e] * OUT_DIM + f);
            a0 += __uint_as_float(v << 16);
            a1 += __uint_as_float(v & 0xFFFF0000u);
        }
        float dn = dinv[node];
        a0 = fmaf(a0, dn, b0);
        a1 = fmaf(a1, dn, b1);
        if (FINAL) {
            ((float2*)outv)[(size_t)node * 64 + lane] = make_float2(a0, a1);
        } else {
            unsigned p = ((unsigned)bf16_rne(a1) << 16) | (unsigned)bf16_rne(a0);
            ((unsigned*)outv)[(size_t)node * 64 + lane] = p;
            s0 += a0; s1 += a1;
            q0 = fmaf(a0, a0, q0); q1 = fmaf(a1, a1, q1);
        }
    }
    if (!FINAL) {
        __shared__ float red[4][256];
        red[wave][f] = s0;        red[wave][f + 1] = s1;
        red[wave][128 + f] = q0;  red[wave][128 + f + 1] = q1;
        __syncthreads();
        int t = threadIdx.x;
        float v = red[0][t] + red[1][t] + red[2][t] + red[3][t];
        atomicAdd(&stats[(blockIdx.x & 7) * 256 + t], v);
    }
}

// ---------------- launch ----------------

extern "C" void kernel_launch(void* const* d_in, const int* in_sizes, int n_in,
                              void* d_out, int out_size, void* d_ws, size_t ws_size,
                              hipStream_t stream) {
    const float* x   = (const float*)d_in[0];
    const int*   ei  = (const int*)d_in[1];
    const float* W1  = (const float*)d_in[2];
    const float* b1  = (const float*)d_in[3];
    const float* W2  = (const float*)d_in[4];
    const float* b2  = (const float*)d_in[5];
    const float* W3  = (const float*)d_in[6];
    const float* b3  = (const float*)d_in[7];
    const float* g1  = (const float*)d_in[8];
    const float* be1 = (const float*)d_in[9];
    const float* g2  = (const float*)d_in[10];
    const float* be2 = (const float*)d_in[11];
    const float* a1  = (const float*)d_in[12];
    const float* a2  = (const float*)d_in[13];

    const int n = N_NODES;
    const int E = in_sizes[1] / 2;
    float* out = (float*)d_out;

    char* ws = (char*)d_ws;
    size_t off = 0;
    auto alloc = [&](size_t bytes) { void* p = ws + off; off += (bytes + 255) & ~(size_t)255; return p; };
    unsigned short* bufA = (unsigned short*)alloc((size_t)n * OUT_DIM * sizeof(short)); // GEMM out (bf16)
    unsigned short* hb   = (unsigned short*)alloc((size_t)n * OUT_DIM * sizeof(short)); // agg out (bf16)
    size_t zero_beg = off;
    int*   cnt   = (int*)alloc((size_t)n * sizeof(int));
    float* stats = (float*)alloc(4096 * sizeof(float));   // 2 layers x 8 replicas x 256
    size_t zero_end = off;
    int*   rowp  = (int*)alloc((size_t)(n + 1) * sizeof(int));
    float* dinv  = (float*)alloc((size_t)n * sizeof(float));
    unsigned short* col = (unsigned short*)alloc((size_t)(E + n) * sizeof(unsigned short));
    unsigned* packed = (unsigned*)alloc((size_t)E * sizeof(unsigned));
    short* Wt1   = (short*)alloc((size_t)IN_DIM * OUT_DIM * sizeof(short));
    short* Wt2   = (short*)alloc((size_t)OUT_DIM * OUT_DIM * sizeof(short));
    short* Wt3   = (short*)alloc((size_t)OUT_DIM * OUT_DIM * sizeof(short));
    int*   psum  = (int*)alloc(64 * sizeof(int));
    int*   pbase = (int*)alloc(64 * sizeof(int));

    const int nbScan = (n + 1023) / 1024;             // 49
    const int chunks = (E + 2047) / 2048;             // 391
    const int partBlocks = 8 * chunks;                // XCD-partitioned edge passes
    const int gblocks = (n + 63) / 64;                // 782
    const int ablocks = 2048;                         // grid-stride agg, 8 blocks/CU

    hipMemsetAsync(ws + zero_beg, 0, zero_end - zero_beg, stream);   // cnt + stats
    hipLaunchKernelGGL(pack_wconv, dim3(chunks + 12), dim3(256), 0, stream,
                       ei, packed, E, W1, Wt1, W2, Wt2, W3, Wt3);
    hipLaunchKernelGGL(deg_kernel, dim3(partBlocks), dim3(256), 0, stream, packed, cnt, E);
    hipLaunchKernelGGL(scan_partial, dim3(nbScan), dim3(1024), 0, stream, cnt, psum, n);
    hipLaunchKernelGGL(scan_base, dim3(1), dim3(64), 0, stream, psum, pbase, rowp, nbScan, n);
    hipLaunchKernelGGL(scan_final, dim3(nbScan), dim3(1024), 0, stream, cnt, pbase, rowp, dinv, col, n);

    // layer 1 GEMM fused with XCD-partitioned packed-edge CSR fill
    hipLaunchKernelGGL(gemm1_fill, dim3(gblocks + partBlocks), dim3(256), 0, stream,
                       x, Wt1, bufA, n, dinv, packed, cnt, col, E, gblocks);
    hipLaunchKernelGGL((agg_kernel<0>), dim3(ablocks), dim3(256), 0, stream,
                       bufA, rowp, col, dinv, b1, hb, stats, n);
    // layer 2
    hipLaunchKernelGGL((mfma_gemm<short, OUT_DIM, true>), dim3(gblocks), dim3(256), 0, stream,
                       (const short*)hb, Wt2, bufA, n, stats, g1, be1, a1, dinv);
    hipLaunchKernelGGL((agg_kernel<0>), dim3(ablocks), dim3(256), 0, stream,
                       bufA, rowp, col, dinv, b2, hb, stats + 2048, n);
    // layer 3
    hipLaunchKernelGGL((mfma_gemm<short, OUT_DIM, true>), dim3(gblocks), dim3(256), 0, stream,
                       (const short*)hb, Wt3, bufA, n, stats + 2048, g2, be2, a2, dinv);
    hipLaunchKernelGGL((agg_kernel<1>), dim3(ablocks), dim3(256), 0, stream,
                       bufA, rowp, col, dinv, b3, out, nullptr, n);
}

// Round 17
// 246.549 us; speedup vs baseline: 1.0736x; 1.0736x over previous
//
#include <hip/hip_runtime.h>

#define N_NODES 50000
#define IN_DIM  512
#define OUT_DIM 128
#define BN_EPS  1e-5f
#define NODES_PER_XCD 6250   // 50000 / 8

typedef __attribute__((ext_vector_type(8))) short short8;
typedef __attribute__((ext_vector_type(4))) float f32x4;

__device__ __forceinline__ unsigned short bf16_rne(float x) {
    unsigned u = __float_as_uint(x);
    unsigned r = (u + 0x7FFFu + ((u >> 16) & 1u)) >> 16;
    return (unsigned short)r;
}
__device__ __forceinline__ float bf16_to_f(unsigned short s) {
    return __uint_as_float(((unsigned)s) << 16);
}

// global -> LDS direct staging, 16B per lane. lds dest is wave-uniform;
// HW adds lane*16.
__device__ __forceinline__ void gload16(const void* g, void* l) {
    __builtin_amdgcn_global_load_lds(
        (const __attribute__((address_space(1))) void*)g,
        (__attribute__((address_space(3))) void*)l, 16, 0, 0);
}

// ---------------- CSR build ----------------

__device__ __forceinline__ int edge_is64(const int* ei) {
    return (ei[1] | ei[3] | ei[5] | ei[7]) == 0;
}

// Pack edges to uint32 (dst<<16 | src; both < 65536) + W convert/transpose.
__global__ __launch_bounds__(256) void pack_wconv(
        const int* __restrict__ ei, unsigned* __restrict__ packed, int E,
        const float* __restrict__ W1, short* __restrict__ Wt1,
        const float* __restrict__ W2, short* __restrict__ Wt2,
        const float* __restrict__ W3, short* __restrict__ Wt3) {
    const int packBlocks = (E + 2047) / 2048;
    const int b = blockIdx.x;
    __shared__ short tile[64][130];
    if (b < packBlocks) {
        const int base = b * 2048;
        const int is64 = edge_is64(ei);
#pragma unroll
        for (int j = 0; j < 8; ++j) {
            int e = base + j * 256 + threadIdx.x;
            if (e < E) {
                int src, dst;
                if (is64) { src = ((const int2*)ei)[e].x; dst = ((const int2*)ei)[E + e].x; }
                else      { src = ei[e];                  dst = ei[E + e]; }
                packed[e] = ((unsigned)dst << 16) | (unsigned)src;
            }
        }
    } else {
        const int wb = b - packBlocks;   // 0..11
        const float* W; short* Wt; int K, k0;
        if (wb < 8)       { W = W1; Wt = Wt1; K = IN_DIM;  k0 = wb * 64; }
        else if (wb < 10) { W = W2; Wt = Wt2; K = OUT_DIM; k0 = (wb - 8) * 64; }
        else              { W = W3; Wt = Wt3; K = OUT_DIM; k0 = (wb - 10) * 64; }
        for (int i = threadIdx.x; i < 64 * 128; i += 256) {
            int k = i >> 7, c = i & 127;
            tile[k][c] = (short)bf16_rne(W[(size_t)(k0 + k) * 128 + c]);
        }
        __syncthreads();
        for (int i = threadIdx.x; i < 64 * 128; i += 256) {
            int c = i >> 6, k = i & 63;
            Wt[(size_t)c * K + k0 + k] = tile[k][c];
        }
    }
}

// XCD-partitioned degree count over the packed edge array.
__global__ __launch_bounds__(256) void deg_kernel(
        const unsigned* __restrict__ packed, int* __restrict__ cnt, int E) {
    const int lo = (blockIdx.x & 7) * NODES_PER_XCD;
    const int hi = lo + NODES_PER_XCD;
    const int base = (blockIdx.x >> 3) * 2048;
#pragma unroll
    for (int j = 0; j < 8; ++j) {
        int e = base + j * 256 + threadIdx.x;
        if (e < E) {
            int dst = (int)(packed[e] >> 16);
            if (dst >= lo && dst < hi) atomicAdd(&cnt[dst], 1);
        }
    }
}

// ---- 3-phase multi-block exclusive scan (deg+1 per node); final phase also
// writes dinv, self-loop entry, and fill cursor ----

__global__ __launch_bounds__(1024) void scan_partial(const int* __restrict__ cnt,
                                                     int* __restrict__ psum, int n) {
    __shared__ int wsum[16];
    const int i = blockIdx.x * 1024 + threadIdx.x;
    const int lane = threadIdx.x & 63;
    const int wv = threadIdx.x >> 6;
    int v = (i < n) ? cnt[i] + 1 : 0;
#pragma unroll
    for (int d = 1; d < 64; d <<= 1) v += __shfl_xor(v, d);
    if (lane == 0) wsum[wv] = v;
    __syncthreads();
    if (threadIdx.x == 0) {
        int t = 0;
#pragma unroll
        for (int w = 0; w < 16; ++w) t += wsum[w];
        psum[blockIdx.x] = t;
    }
}

__global__ void scan_base(const int* __restrict__ psum, int* __restrict__ pbase,
                          int* __restrict__ rowp, int nb, int n) {
    const int lane = threadIdx.x;   // 64
    int orig = (lane < nb) ? psum[lane] : 0;
    int v = orig;
#pragma unroll
    for (int d = 1; d < 64; d <<= 1) {
        int t = __shfl_up(v, d);
        if (lane >= d) v += t;
    }
    if (lane < nb) pbase[lane] = v - orig;
    if (lane == nb - 1) rowp[n] = v;
}

__global__ __launch_bounds__(1024) void scan_final(int* __restrict__ cnt,
                                                   const int* __restrict__ pbase,
                                                   int* __restrict__ rowp,
                                                   float* __restrict__ dinv,
                                                   unsigned short* __restrict__ col, int n) {
    __shared__ int wsum[16];
    const int i = blockIdx.x * 1024 + threadIdx.x;
    const int lane = threadIdx.x & 63;
    const int wv = threadIdx.x >> 6;
    int orig = (i < n) ? cnt[i] + 1 : 0;    // degree incl self-loop
    int v = orig;
#pragma unroll
    for (int d = 1; d < 64; d <<= 1) {
        int t = __shfl_up(v, d);
        if (lane >= d) v += t;
    }
    if (lane == 63) wsum[wv] = v;
    __syncthreads();
    int woff = 0;
    for (int w = 0; w < wv; ++w) woff += wsum[w];
    if (i < n) {
        int rp = pbase[blockIdx.x] + woff + v - orig;
        rowp[i] = rp;
        dinv[i] = rsqrtf(fmaxf((float)orig, 1.f));
        col[rp] = (unsigned short)i;   // self loop first
        cnt[i] = rp + 1;               // cursor for edge fill
    }
}

// ---------------- MFMA GEMM body (device fn; bid = tile index) ----------------

template <typename TA, int K, bool XFORM>
__device__ __forceinline__ void gemm_body(
        int bid, const TA* __restrict__ A, const short* __restrict__ Wt,
        unsigned short* __restrict__ out, int M,
        const float* __restrict__ stats, const float* __restrict__ gam,
        const float* __restrict__ bet, const float* __restrict__ alpha_p,
        const float* __restrict__ dinv) {
    constexpr int BK = 64;
    constexpr int NSTEP = K / BK;
    constexpr int UPRA = (BK * (int)sizeof(TA)) / 16;   // 16B units per A row
    constexpr int AINST = 64 * UPRA / 256;              // 4 (fp32) or 2 (bf16)
    __shared__ TA    ldsA[64 * BK];
    __shared__ short ldsB[128 * BK];
    __shared__ float bnp[256];

    const int tid  = threadIdx.x;
    const int lane = tid & 63;
    const int wv   = tid >> 6;
    const int r16  = lane & 15;
    const int g    = lane >> 4;
    const int row0 = bid * 64;
    const int arow_t = wv * 16 + r16;

    float alpha = 0.f;
    if constexpr (XFORM) {
        alpha = alpha_p[0];
        if (tid < 128) {
            float sum = 0.f, sq = 0.f;
#pragma unroll
            for (int r = 0; r < 8; ++r) {
                sum += stats[r * 256 + tid];
                sq  += stats[r * 256 + 128 + tid];
            }
            const float inv_n = 1.0f / (float)N_NODES;
            float mean = sum * inv_n;
            float var = fmaxf(sq * inv_n - mean * mean, 0.f);
            float sc = gam[tid] * rsqrtf(var + BN_EPS);
            bnp[tid] = sc;
            bnp[128 + tid] = bet[tid] - mean * sc;
        }
        __syncthreads();
    }

    f32x4 acc[8];
#pragma unroll
    for (int nf = 0; nf < 8; nf++) acc[nf] = (f32x4)(0.f);

    for (int s = 0; s < NSTEP; ++s) {
        const int k0 = s * BK;
        if (s) __syncthreads();
#pragma unroll
        for (int i = 0; i < AINST; ++i) {
            const int d   = i * 256 + tid;
            const int row = d / UPRA, p = d % UPRA;
            int grow = row0 + row; if (grow >= M) grow = M - 1;
            const char* src = (const char*)(A + (size_t)grow * K + k0) + ((p ^ (row & 7)) * 16);
            gload16(src, (char*)ldsA + (size_t)(i * 256 + wv * 64) * 16);
        }
#pragma unroll
        for (int i = 0; i < 4; ++i) {
            const int d    = i * 256 + tid;
            const int colb = d >> 3, p = d & 7;
            const short* src = Wt + (size_t)colb * K + k0 + (p ^ (colb & 7)) * 8;
            gload16(src, (char*)ldsB + (size_t)(i * 256 + wv * 64) * 16);
        }
        __syncthreads();
#pragma unroll
        for (int ksub = 0; ksub < 2; ++ksub) {
            short8 af;
            if constexpr (sizeof(TA) == 4) {
                const int q0 = ksub * 8 + g * 2;
                const float4* A4 = (const float4*)ldsA;
                float4 alo = A4[arow_t * UPRA + (q0 ^ (r16 & 7))];
                float4 ahi = A4[arow_t * UPRA + ((q0 + 1) ^ (r16 & 7))];
                float av[8] = {alo.x, alo.y, alo.z, alo.w, ahi.x, ahi.y, ahi.z, ahi.w};
#pragma unroll
                for (int j = 0; j < 8; j++) af[j] = (short)bf16_rne(av[j]);
            } else {
                short8 raw = ((const short8*)ldsA)[arow_t * 8 + ((ksub * 4 + g) ^ (r16 & 7))];
                if constexpr (XFORM) {
                    const int kb = k0 + ksub * 32 + g * 8;
#pragma unroll
                    for (int j = 0; j < 8; j++) {
                        float v = fmaf(bf16_to_f((unsigned short)raw[j]), bnp[kb + j], bnp[128 + kb + j]);
                        v = v >= 0.f ? v : alpha * v;
                        af[j] = (short)bf16_rne(v);
                    }
                } else {
                    af = raw;
                }
            }
#pragma unroll
            for (int nf = 0; nf < 8; nf++) {
                const int colb = nf * 16 + r16;
                short8 bf = ((const short8*)ldsB)[colb * 8 + ((ksub * 4 + g) ^ (r16 & 7))];
                acc[nf] = __builtin_amdgcn_mfma_f32_16x16x32_bf16(af, bf, acc[nf], 0, 0, 0);
            }
        }
    }

    // epilogue: acc -> LDS (bf16, reuse ldsB) -> coalesced stores
    __syncthreads();
    unsigned short* ot = (unsigned short*)ldsB;
#pragma unroll
    for (int r = 0; r < 4; ++r) {
        const int trow = wv * 16 + g * 4 + r;
        const int grow = row0 + trow;
        const float dv = (grow < M) ? dinv[grow] : 0.f;
#pragma unroll
        for (int nf = 0; nf < 8; nf++)
            ot[trow * 128 + nf * 16 + r16] = bf16_rne(acc[nf][r] * dv);
    }
    __syncthreads();
    {
        const int trow = wv * 16 + r16;
        const int seg  = g;
        const int grow = row0 + trow;
        if (grow < M) {
            const float4* lsrc = (const float4*)ot + trow * 16 + seg * 4;
            float4* gdst = (float4*)((char*)out + (size_t)grow * 256) + seg * 4;
#pragma unroll
            for (int i = 0; i < 4; ++i) gdst[i] = lsrc[i];
        }
    }
}

// ---------------- fused GEMM1 + XCD-partitioned CSR fill (packed reads) ----

__global__ __launch_bounds__(256) void gemm1_fill(
        const float* __restrict__ A, const short* __restrict__ Wt,
        unsigned short* __restrict__ out, int M, const float* __restrict__ dinv,
        const unsigned* __restrict__ packed, int* __restrict__ cnt,
        unsigned short* __restrict__ col, int E, int gblocks) {
    if ((int)blockIdx.x < gblocks) {
        gemm_body<float, IN_DIM, false>(blockIdx.x, A, Wt, out, M,
                                        nullptr, nullptr, nullptr, nullptr, dinv);
    } else {
        const int fb = blockIdx.x - gblocks;
        const int lo = (fb & 7) * NODES_PER_XCD;
        const int hi = lo + NODES_PER_XCD;
        const int base = (fb >> 3) * 2048;
#pragma unroll
        for (int j = 0; j < 8; ++j) {
            int e = base + j * 256 + threadIdx.x;
            if (e < E) {
                unsigned p = packed[e];
                int dst = (int)(p >> 16);
                if (dst >= lo && dst < hi) {
                    int pos = atomicAdd(&cnt[dst], 1);
                    col[pos] = (unsigned short)(p & 0xFFFFu);
                }
            }
        }
    }
}

template <typename TA, int K, bool XFORM>
__global__ __launch_bounds__(256) void mfma_gemm(
        const TA* __restrict__ A, const short* __restrict__ Wt,
        unsigned short* __restrict__ out, int M,
        const float* __restrict__ stats, const float* __restrict__ gam,
        const float* __restrict__ bet, const float* __restrict__ alpha_p,
        const float* __restrict__ dinv) {
    gemm_body<TA, K, XFORM>(blockIdx.x, A, Wt, out, M, stats, gam, bet, alpha_p, dinv);
}

// ---------------- Aggregation + fused BN stats ----------------
// Masked full-width batches: the degree tail is a predicated 8-wide batch
// (clamped col index, contribution zeroed) instead of a serial scalar loop,
// so every node is ceil(deg/8) fully-parallel gather batches.

template <int FINAL>
__global__ __launch_bounds__(256) void agg_kernel(
        const unsigned short* __restrict__ h, const int* __restrict__ rowp,
        const unsigned short* __restrict__ col, const float* __restrict__ dinv,
        const float* __restrict__ bias, void* __restrict__ outv,
        float* __restrict__ stats, int n) {
    const int wave = threadIdx.x >> 6;
    const int lane = threadIdx.x & 63;
    const int f = lane << 1;
    const float b0 = bias[f], b1 = bias[f + 1];
    float s0 = 0.f, s1 = 0.f, q0 = 0.f, q1 = 0.f;
    const int stride = gridDim.x << 2;
    for (int node = (blockIdx.x << 2) + wave; node < n; node += stride) {
        const int beg = rowp[node];
        const int end = rowp[node + 1];
        float a0 = 0.f, a1 = 0.f;
        for (int e = beg; e < end; e += 8) {
            int c[8];
#pragma unroll
            for (int j = 0; j < 8; j++) {
                int idx = e + j;
                c[j] = col[idx < end ? idx : end - 1];
            }
            unsigned v[8];
#pragma unroll
            for (int j = 0; j < 8; j++)
                v[j] = *(const unsigned*)(h + (size_t)c[j] * OUT_DIM + f);
#pragma unroll
            for (int j = 0; j < 8; j++) {
                unsigned vv = (e + j < end) ? v[j] : 0u;
                a0 += __uint_as_float(vv << 16);
                a1 += __uint_as_float(vv & 0xFFFF0000u);
            }
        }
        float dn = dinv[node];
        a0 = fmaf(a0, dn, b0);
        a1 = fmaf(a1, dn, b1);
        if (FINAL) {
            ((float2*)outv)[(size_t)node * 64 + lane] = make_float2(a0, a1);
        } else {
            unsigned p = ((unsigned)bf16_rne(a1) << 16) | (unsigned)bf16_rne(a0);
            ((unsigned*)outv)[(size_t)node * 64 + lane] = p;
            s0 += a0; s1 += a1;
            q0 = fmaf(a0, a0, q0); q1 = fmaf(a1, a1, q1);
        }
    }
    if (!FINAL) {
        __shared__ float red[4][256];
        red[wave][f] = s0;        red[wave][f + 1] = s1;
        red[wave][128 + f] = q0;  red[wave][128 + f + 1] = q1;
        __syncthreads();
        int t = threadIdx.x;
        float v = red[0][t] + red[1][t] + red[2][t] + red[3][t];
        atomicAdd(&stats[(blockIdx.x & 7) * 256 + t], v);
    }
}

// ---------------- launch ----------------

extern "C" void kernel_launch(void* const* d_in, const int* in_sizes, int n_in,
                              void* d_out, int out_size, void* d_ws, size_t ws_size,
                              hipStream_t stream) {
    const float* x   = (const float*)d_in[0];
    const int*   ei  = (const int*)d_in[1];
    const float* W1  = (const float*)d_in[2];
    const float* b1  = (const float*)d_in[3];
    const float* W2  = (const float*)d_in[4];
    const float* b2  = (const float*)d_in[5];
    const float* W3  = (const float*)d_in[6];
    const float* b3  = (const float*)d_in[7];
    const float* g1  = (const float*)d_in[8];
    const float* be1 = (const float*)d_in[9];
    const float* g2  = (const float*)d_in[10];
    const float* be2 = (const float*)d_in[11];
    const float* a1  = (const float*)d_in[12];
    const float* a2  = (const float*)d_in[13];

    const int n = N_NODES;
    const int E = in_sizes[1] / 2;
    float* out = (float*)d_out;

    char* ws = (char*)d_ws;
    size_t off = 0;
    auto alloc = [&](size_t bytes) { void* p = ws + off; off += (bytes + 255) & ~(size_t)255; return p; };
    unsigned short* bufA = (unsigned short*)alloc((size_t)n * OUT_DIM * sizeof(short)); // GEMM out (bf16)
    unsigned short* hb   = (unsigned short*)alloc((size_t)n * OUT_DIM * sizeof(short)); // agg out (bf16)
    size_t zero_beg = off;
    int*   cnt   = (int*)alloc((size_t)n * sizeof(int));
    float* stats = (float*)alloc(4096 * sizeof(float));   // 2 layers x 8 replicas x 256
    size_t zero_end = off;
    int*   rowp  = (int*)alloc((size_t)(n + 1) * sizeof(int));
    float* dinv  = (float*)alloc((size_t)n * sizeof(float));
    unsigned short* col = (unsigned short*)alloc((size_t)(E + n) * sizeof(unsigned short));
    unsigned* packed = (unsigned*)alloc((size_t)E * sizeof(unsigned));
    short* Wt1   = (short*)alloc((size_t)IN_DIM * OUT_DIM * sizeof(short));
    short* Wt2   = (short*)alloc((size_t)OUT_DIM * OUT_DIM * sizeof(short));
    short* Wt3   = (short*)alloc((size_t)OUT_DIM * OUT_DIM * sizeof(short));
    int*   psum  = (int*)alloc(64 * sizeof(int));
    int*   pbase = (int*)alloc(64 * sizeof(int));

    const int nbScan = (n + 1023) / 1024;             // 49
    const int chunks = (E + 2047) / 2048;             // 391
    const int partBlocks = 8 * chunks;                // XCD-partitioned edge passes
    const int gblocks = (n + 63) / 64;                // 782
    const int ablocks = 2048;                         // grid-stride agg, 8 blocks/CU

    hipMemsetAsync(ws + zero_beg, 0, zero_end - zero_beg, stream);   // cnt + stats
    hipLaunchKernelGGL(pack_wconv, dim3(chunks + 12), dim3(256), 0, stream,
                       ei, packed, E, W1, Wt1, W2, Wt2, W3, Wt3);
    hipLaunchKernelGGL(deg_kernel, dim3(partBlocks), dim3(256), 0, stream, packed, cnt, E);
    hipLaunchKernelGGL(scan_partial, dim3(nbScan), dim3(1024), 0, stream, cnt, psum, n);
    hipLaunchKernelGGL(scan_base, dim3(1), dim3(64), 0, stream, psum, pbase, rowp, nbScan, n);
    hipLaunchKernelGGL(scan_final, dim3(nbScan), dim3(1024), 0, stream, cnt, pbase, rowp, dinv, col, n);

    // layer 1 GEMM fused with XCD-partitioned packed-edge CSR fill
    hipLaunchKernelGGL(gemm1_fill, dim3(gblocks + partBlocks), dim3(256), 0, stream,
                       x, Wt1, bufA, n, dinv, packed, cnt, col, E, gblocks);
    hipLaunchKernelGGL((agg_kernel<0>), dim3(ablocks), dim3(256), 0, stream,
                       bufA, rowp, col, dinv, b1, hb, stats, n);
    // layer 2
    hipLaunchKernelGGL((mfma_gemm<short, OUT_DIM, true>), dim3(gblocks), dim3(256), 0, stream,
                       (const short*)hb, Wt2, bufA, n, stats, g1, be1, a1, dinv);
    hipLaunchKernelGGL((agg_kernel<0>), dim3(ablocks), dim3(256), 0, stream,
                       bufA, rowp, col, dinv, b2, hb, stats + 2048, n);
    // layer 3
    hipLaunchKernelGGL((mfma_gemm<short, OUT_DIM, true>), dim3(gblocks), dim3(256), 0, stream,
                       (const short*)hb, Wt3, bufA, n, stats + 2048, g2, be2, a2, dinv);
    hipLaunchKernelGGL((agg_kernel<1>), dim3(ablocks), dim3(256), 0, stream,
                       bufA, rowp, col, dinv, b3, out, nullptr, n);
}

// Round 18
// 240.367 us; speedup vs baseline: 1.1012x; 1.0257x over previous
//
#include <hip/hip_runtime.h>

#define N_NODES 50000
#define IN_DIM  512
#define OUT_DIM 128
#define BN_EPS  1e-5f
#define NODES_PER_XCD 6250   // 50000 / 8

typedef __attribute__((ext_vector_type(8))) short short8;
typedef __attribute__((ext_vector_type(4))) float f32x4;

__device__ __forceinline__ unsigned short bf16_rne(float x) {
    unsigned u = __float_as_uint(x);
    unsigned r = (u + 0x7FFFu + ((u >> 16) & 1u)) >> 16;
    return (unsigned short)r;
}
__device__ __forceinline__ float bf16_to_f(unsigned short s) {
    return __uint_as_float(((unsigned)s) << 16);
}

// global -> LDS direct staging, 16B per lane. lds dest is wave-uniform;
// HW adds lane*16.
__device__ __forceinline__ void gload16(const void* g, void* l) {
    __builtin_amdgcn_global_load_lds(
        (const __attribute__((address_space(1))) void*)g,
        (__attribute__((address_space(3))) void*)l, 16, 0, 0);
}

// ---------------- CSR build ----------------

__device__ __forceinline__ int edge_is64(const int* ei) {
    return (ei[1] | ei[3] | ei[5] | ei[7]) == 0;
}

// Pack edges to uint32 (dst<<16 | src; both < 65536) + W convert/transpose.
__global__ __launch_bounds__(256) void pack_wconv(
        const int* __restrict__ ei, unsigned* __restrict__ packed, int E,
        const float* __restrict__ W1, short* __restrict__ Wt1,
        const float* __restrict__ W2, short* __restrict__ Wt2,
        const float* __restrict__ W3, short* __restrict__ Wt3) {
    const int packBlocks = (E + 2047) / 2048;
    const int b = blockIdx.x;
    __shared__ short tile[64][130];
    if (b < packBlocks) {
        const int base = b * 2048;
        const int is64 = edge_is64(ei);
#pragma unroll
        for (int j = 0; j < 8; ++j) {
            int e = base + j * 256 + threadIdx.x;
            if (e < E) {
                int src, dst;
                if (is64) { src = ((const int2*)ei)[e].x; dst = ((const int2*)ei)[E + e].x; }
                else      { src = ei[e];                  dst = ei[E + e]; }
                packed[e] = ((unsigned)dst << 16) | (unsigned)src;
            }
        }
    } else {
        const int wb = b - packBlocks;   // 0..11
        const float* W; short* Wt; int K, k0;
        if (wb < 8)       { W = W1; Wt = Wt1; K = IN_DIM;  k0 = wb * 64; }
        else if (wb < 10) { W = W2; Wt = Wt2; K = OUT_DIM; k0 = (wb - 8) * 64; }
        else              { W = W3; Wt = Wt3; K = OUT_DIM; k0 = (wb - 10) * 64; }
        for (int i = threadIdx.x; i < 64 * 128; i += 256) {
            int k = i >> 7, c = i & 127;
            tile[k][c] = (short)bf16_rne(W[(size_t)(k0 + k) * 128 + c]);
        }
        __syncthreads();
        for (int i = threadIdx.x; i < 64 * 128; i += 256) {
            int c = i >> 6, k = i & 63;
            Wt[(size_t)c * K + k0 + k] = tile[k][c];
        }
    }
}

// XCD-partitioned degree count over the packed edge array.
__global__ __launch_bounds__(256) void deg_kernel(
        const unsigned* __restrict__ packed, int* __restrict__ cnt, int E) {
    const int lo = (blockIdx.x & 7) * NODES_PER_XCD;
    const int hi = lo + NODES_PER_XCD;
    const int base = (blockIdx.x >> 3) * 2048;
#pragma unroll
    for (int j = 0; j < 8; ++j) {
        int e = base + j * 256 + threadIdx.x;
        if (e < E) {
            int dst = (int)(packed[e] >> 16);
            if (dst >= lo && dst < hi) atomicAdd(&cnt[dst], 1);
        }
    }
}

// ---- 3-phase multi-block exclusive scan (deg+1 per node); final phase also
// writes dinv, self-loop entry, and fill cursor ----

__global__ __launch_bounds__(1024) void scan_partial(const int* __restrict__ cnt,
                                                     int* __restrict__ psum, int n) {
    __shared__ int wsum[16];
    const int i = blockIdx.x * 1024 + threadIdx.x;
    const int lane = threadIdx.x & 63;
    const int wv = threadIdx.x >> 6;
    int v = (i < n) ? cnt[i] + 1 : 0;
#pragma unroll
    for (int d = 1; d < 64; d <<= 1) v += __shfl_xor(v, d);
    if (lane == 0) wsum[wv] = v;
    __syncthreads();
    if (threadIdx.x == 0) {
        int t = 0;
#pragma unroll
        for (int w = 0; w < 16; ++w) t += wsum[w];
        psum[blockIdx.x] = t;
    }
}

__global__ void scan_base(const int* __restrict__ psum, int* __restrict__ pbase,
                          int* __restrict__ rowp, int nb, int n) {
    const int lane = threadIdx.x;   // 64
    int orig = (lane < nb) ? psum[lane] : 0;
    int v = orig;
#pragma unroll
    for (int d = 1; d < 64; d <<= 1) {
        int t = __shfl_up(v, d);
        if (lane >= d) v += t;
    }
    if (lane < nb) pbase[lane] = v - orig;
    if (lane == nb - 1) rowp[n] = v;
}

__global__ __launch_bounds__(1024) void scan_final(int* __restrict__ cnt,
                                                   const int* __restrict__ pbase,
                                                   int* __restrict__ rowp,
                                                   float* __restrict__ dinv,
                                                   unsigned short* __restrict__ col, int n) {
    __shared__ int wsum[16];
    const int i = blockIdx.x * 1024 + threadIdx.x;
    const int lane = threadIdx.x & 63;
    const int wv = threadIdx.x >> 6;
    int orig = (i < n) ? cnt[i] + 1 : 0;    // degree incl self-loop
    int v = orig;
#pragma unroll
    for (int d = 1; d < 64; d <<= 1) {
        int t = __shfl_up(v, d);
        if (lane >= d) v += t;
    }
    if (lane == 63) wsum[wv] = v;
    __syncthreads();
    int woff = 0;
    for (int w = 0; w < wv; ++w) woff += wsum[w];
    if (i < n) {
        int rp = pbase[blockIdx.x] + woff + v - orig;
        rowp[i] = rp;
        dinv[i] = rsqrtf(fmaxf((float)orig, 1.f));
        col[rp] = (unsigned short)i;   // self loop first
        cnt[i] = rp + 1;               // cursor for edge fill
    }
}

// ---------------- MFMA GEMM body (device fn; bid = tile index) ----------------
// m97 structure: global_load_lds staged, single buffer, XOR-swizzled.
// BK templated: gemm1 uses BK=32 (17KB LDS -> 8 blocks/CU so co-resident fill
// blocks in the fused kernel get full TLP); bf16 gemms use BK=64.
// XFORM: fused BN finalize (8 replicas) + BN+PReLU on A fragments.
// Epilogue: *dinv[row], staged through the (ldsA|ldsB) region, coalesced.

template <typename TA, int K, int BK, bool XFORM>
__device__ __forceinline__ void gemm_body(
        int bid, const TA* __restrict__ A, const short* __restrict__ Wt,
        unsigned short* __restrict__ out, int M,
        const float* __restrict__ stats, const float* __restrict__ gam,
        const float* __restrict__ bet, const float* __restrict__ alpha_p,
        const float* __restrict__ dinv) {
    constexpr int NSTEP = K / BK;
    constexpr int UPRA  = (BK * (int)sizeof(TA)) / 16;  // 16B units per A row
    constexpr int AINST = 64 * UPRA / 256;
    constexpr int UPRB  = (BK * 2) / 16;                // 16B units per B col
    constexpr int BINST = 128 * UPRB / 256;
    constexpr int ASZ   = 64 * BK * (int)sizeof(TA);
    constexpr int BSZ   = 128 * BK * 2;
    constexpr int SMSZ  = (ASZ + BSZ) > 16384 ? (ASZ + BSZ) : 16384;
    __shared__ __align__(16) char smem[SMSZ];
    __shared__ float bnp[256];
    TA*    ldsA = (TA*)smem;
    short* ldsB = (short*)(smem + ASZ);

    const int tid  = threadIdx.x;
    const int lane = tid & 63;
    const int wv   = tid >> 6;
    const int r16  = lane & 15;
    const int g    = lane >> 4;
    const int row0 = bid * 64;
    const int arow_t = wv * 16 + r16;

    float alpha = 0.f;
    if constexpr (XFORM) {
        alpha = alpha_p[0];
        if (tid < 128) {
            float sum = 0.f, sq = 0.f;
#pragma unroll
            for (int r = 0; r < 8; ++r) {
                sum += stats[r * 256 + tid];
                sq  += stats[r * 256 + 128 + tid];
            }
            const float inv_n = 1.0f / (float)N_NODES;
            float mean = sum * inv_n;
            float var = fmaxf(sq * inv_n - mean * mean, 0.f);
            float sc = gam[tid] * rsqrtf(var + BN_EPS);
            bnp[tid] = sc;
            bnp[128 + tid] = bet[tid] - mean * sc;
        }
        __syncthreads();
    }

    f32x4 acc[8];
#pragma unroll
    for (int nf = 0; nf < 8; nf++) acc[nf] = (f32x4)(0.f);

    for (int s = 0; s < NSTEP; ++s) {
        const int k0 = s * BK;
        if (s) __syncthreads();
#pragma unroll
        for (int i = 0; i < AINST; ++i) {
            const int d   = i * 256 + tid;
            const int row = d / UPRA, p = d % UPRA;
            int grow = row0 + row; if (grow >= M) grow = M - 1;
            const char* src = (const char*)(A + (size_t)grow * K + k0) + ((p ^ (row & 7)) * 16);
            gload16(src, (char*)ldsA + (size_t)(i * 256 + wv * 64) * 16);
        }
#pragma unroll
        for (int i = 0; i < BINST; ++i) {
            const int d    = i * 256 + tid;
            const int colb = d / UPRB, p = d % UPRB;
            const int sw   = (UPRB == 8) ? (colb & 7) : ((colb >> 2) & 3);
            const short* src = Wt + (size_t)colb * K + k0 + (p ^ sw) * 8;
            gload16(src, (char*)ldsB + (size_t)(i * 256 + wv * 64) * 16);
        }
        __syncthreads();
#pragma unroll
        for (int ksub = 0; ksub < BK / 32; ++ksub) {
            short8 af;
            if constexpr (sizeof(TA) == 4) {
                const int q0 = ksub * 8 + g * 2;
                const float4* A4 = (const float4*)ldsA;
                float4 alo = A4[arow_t * UPRA + ((q0 + 0) ^ (r16 & 7))];
                float4 ahi = A4[arow_t * UPRA + ((q0 + 1) ^ (r16 & 7))];
                float av[8] = {alo.x, alo.y, alo.z, alo.w, ahi.x, ahi.y, ahi.z, ahi.w};
#pragma unroll
                for (int j = 0; j < 8; j++) af[j] = (short)bf16_rne(av[j]);
            } else {
                short8 raw = ((const short8*)ldsA)[arow_t * UPRA + ((ksub * 4 + g) ^ (r16 & 7))];
                if constexpr (XFORM) {
                    const int kb = k0 + ksub * 32 + g * 8;
#pragma unroll
                    for (int j = 0; j < 8; j++) {
                        float v = fmaf(bf16_to_f((unsigned short)raw[j]), bnp[kb + j], bnp[128 + kb + j]);
                        v = v >= 0.f ? v : alpha * v;
                        af[j] = (short)bf16_rne(v);
                    }
                } else {
                    af = raw;
                }
            }
#pragma unroll
            for (int nf = 0; nf < 8; nf++) {
                const int colb = nf * 16 + r16;
                const int sw   = (UPRB == 8) ? (colb & 7) : ((colb >> 2) & 3);
                short8 bf = ((const short8*)ldsB)[colb * UPRB + ((ksub * 4 + g) ^ sw)];
                acc[nf] = __builtin_amdgcn_mfma_f32_16x16x32_bf16(af, bf, acc[nf], 0, 0, 0);
            }
        }
    }

    // epilogue: acc -> LDS (bf16, 64x128 = 16KB over smem) -> coalesced stores
    __syncthreads();
    unsigned short* ot = (unsigned short*)smem;
#pragma unroll
    for (int r = 0; r < 4; ++r) {
        const int trow = wv * 16 + g * 4 + r;
        const int grow = row0 + trow;
        const float dv = (grow < M) ? dinv[grow] : 0.f;
#pragma unroll
        for (int nf = 0; nf < 8; nf++)
            ot[trow * 128 + nf * 16 + r16] = bf16_rne(acc[nf][r] * dv);
    }
    __syncthreads();
    {
        const int trow = wv * 16 + r16;
        const int seg  = g;
        const int grow = row0 + trow;
        if (grow < M) {
            const float4* lsrc = (const float4*)ot + trow * 16 + seg * 4;
            float4* gdst = (float4*)((char*)out + (size_t)grow * 256) + seg * 4;
#pragma unroll
            for (int i = 0; i < 4; ++i) gdst[i] = lsrc[i];
        }
    }
}

// ---------------- fused GEMM1 (BK=32) + XCD-partitioned CSR fill ----------------

__global__ __launch_bounds__(256) void gemm1_fill(
        const float* __restrict__ A, const short* __restrict__ Wt,
        unsigned short* __restrict__ out, int M, const float* __restrict__ dinv,
        const unsigned* __restrict__ packed, int* __restrict__ cnt,
        unsigned short* __restrict__ col, int E, int gblocks) {
    if ((int)blockIdx.x < gblocks) {
        gemm_body<float, IN_DIM, 32, false>(blockIdx.x, A, Wt, out, M,
                                            nullptr, nullptr, nullptr, nullptr, dinv);
    } else {
        const int fb = blockIdx.x - gblocks;
        const int lo = (fb & 7) * NODES_PER_XCD;
        const int hi = lo + NODES_PER_XCD;
        const int base = (fb >> 3) * 2048;
#pragma unroll
        for (int j = 0; j < 8; ++j) {
            int e = base + j * 256 + threadIdx.x;
            if (e < E) {
                unsigned p = packed[e];
                int dst = (int)(p >> 16);
                if (dst >= lo && dst < hi) {
                    int pos = atomicAdd(&cnt[dst], 1);
                    col[pos] = (unsigned short)(p & 0xFFFFu);
                }
            }
        }
    }
}

template <typename TA, int K, int BK, bool XFORM>
__global__ __launch_bounds__(256) void mfma_gemm(
        const TA* __restrict__ A, const short* __restrict__ Wt,
        unsigned short* __restrict__ out, int M,
        const float* __restrict__ stats, const float* __restrict__ gam,
        const float* __restrict__ bet, const float* __restrict__ alpha_p,
        const float* __restrict__ dinv) {
    gemm_body<TA, K, BK, XFORM>(blockIdx.x, A, Wt, out, M, stats, gam, bet, alpha_p, dinv);
}

// ---------------- Aggregation + fused BN stats ----------------
// Masked full-width batches (no serial degree tail).

template <int FINAL>
__global__ __launch_bounds__(256) void agg_kernel(
        const unsigned short* __restrict__ h, const int* __restrict__ rowp,
        const unsigned short* __restrict__ col, const float* __restrict__ dinv,
        const float* __restrict__ bias, void* __restrict__ outv,
        float* __restrict__ stats, int n) {
    const int wave = threadIdx.x >> 6;
    const int lane = threadIdx.x & 63;
    const int f = lane << 1;
    const float b0 = bias[f], b1 = bias[f + 1];
    float s0 = 0.f, s1 = 0.f, q0 = 0.f, q1 = 0.f;
    const int stride = gridDim.x << 2;
    for (int node = (blockIdx.x << 2) + wave; node < n; node += stride) {
        const int beg = rowp[node];
        const int end = rowp[node + 1];
        float a0 = 0.f, a1 = 0.f;
        for (int e = beg; e < end; e += 8) {
            int c[8];
#pragma unroll
            for (int j = 0; j < 8; j++) {
                int idx = e + j;
                c[j] = col[idx < end ? idx : end - 1];
            }
            unsigned v[8];
#pragma unroll
            for (int j = 0; j < 8; j++)
                v[j] = *(const unsigned*)(h + (size_t)c[j] * OUT_DIM + f);
#pragma unroll
            for (int j = 0; j < 8; j++) {
                unsigned vv = (e + j < end) ? v[j] : 0u;
                a0 += __uint_as_float(vv << 16);
                a1 += __uint_as_float(vv & 0xFFFF0000u);
            }
        }
        float dn = dinv[node];
        a0 = fmaf(a0, dn, b0);
        a1 = fmaf(a1, dn, b1);
        if (FINAL) {
            ((float2*)outv)[(size_t)node * 64 + lane] = make_float2(a0, a1);
        } else {
            unsigned p = ((unsigned)bf16_rne(a1) << 16) | (unsigned)bf16_rne(a0);
            ((unsigned*)outv)[(size_t)node * 64 + lane] = p;
            s0 += a0; s1 += a1;
            q0 = fmaf(a0, a0, q0); q1 = fmaf(a1, a1, q1);
        }
    }
    if (!FINAL) {
        __shared__ float red[4][256];
        red[wave][f] = s0;        red[wave][f + 1] = s1;
        red[wave][128 + f] = q0;  red[wave][128 + f + 1] = q1;
        __syncthreads();
        int t = threadIdx.x;
        float v = red[0][t] + red[1][t] + red[2][t] + red[3][t];
        atomicAdd(&stats[(blockIdx.x & 7) * 256 + t], v);
    }
}

// ---------------- launch ----------------

extern "C" void kernel_launch(void* const* d_in, const int* in_sizes, int n_in,
                              void* d_out, int out_size, void* d_ws, size_t ws_size,
                              hipStream_t stream) {
    const float* x   = (const float*)d_in[0];
    const int*   ei  = (const int*)d_in[1];
    const float* W1  = (const float*)d_in[2];
    const float* b1  = (const float*)d_in[3];
    const float* W2  = (const float*)d_in[4];
    const float* b2  = (const float*)d_in[5];
    const float* W3  = (const float*)d_in[6];
    const float* b3  = (const float*)d_in[7];
    const float* g1  = (const float*)d_in[8];
    const float* be1 = (const float*)d_in[9];
    const float* g2  = (const float*)d_in[10];
    const float* be2 = (const float*)d_in[11];
    const float* a1  = (const float*)d_in[12];
    const float* a2  = (const float*)d_in[13];

    const int n = N_NODES;
    const int E = in_sizes[1] / 2;
    float* out = (float*)d_out;

    char* ws = (char*)d_ws;
    size_t off = 0;
    auto alloc = [&](size_t bytes) { void* p = ws + off; off += (bytes + 255) & ~(size_t)255; return p; };
    unsigned short* bufA = (unsigned short*)alloc((size_t)n * OUT_DIM * sizeof(short)); // GEMM out (bf16)
    unsigned short* hb   = (unsigned short*)alloc((size_t)n * OUT_DIM * sizeof(short)); // agg out (bf16)
    size_t zero_beg = off;
    int*   cnt   = (int*)alloc((size_t)n * sizeof(int));
    float* stats = (float*)alloc(4096 * sizeof(float));   // 2 layers x 8 replicas x 256
    size_t zero_end = off;
    int*   rowp  = (int*)alloc((size_t)(n + 1) * sizeof(int));
    float* dinv  = (float*)alloc((size_t)n * sizeof(float));
    unsigned short* col = (unsigned short*)alloc((size_t)(E + n) * sizeof(unsigned short));
    unsigned* packed = (unsigned*)alloc((size_t)E * sizeof(unsigned));
    short* Wt1   = (short*)alloc((size_t)IN_DIM * OUT_DIM * sizeof(short));
    short* Wt2   = (short*)alloc((size_t)OUT_DIM * OUT_DIM * sizeof(short));
    short* Wt3   = (short*)alloc((size_t)OUT_DIM * OUT_DIM * sizeof(short));
    int*   psum  = (int*)alloc(64 * sizeof(int));
    int*   pbase = (int*)alloc(64 * sizeof(int));

    const int nbScan = (n + 1023) / 1024;             // 49
    const int chunks = (E + 2047) / 2048;             // 391
    const int partBlocks = 8 * chunks;                // XCD-partitioned edge passes
    const int gblocks = (n + 63) / 64;                // 782
    const int ablocks = 2048;                         // grid-stride agg, 8 blocks/CU

    hipMemsetAsync(ws + zero_beg, 0, zero_end - zero_beg, stream);   // cnt + stats
    hipLaunchKernelGGL(pack_wconv, dim3(chunks + 12), dim3(256), 0, stream,
                       ei, packed, E, W1, Wt1, W2, Wt2, W3, Wt3);
    hipLaunchKernelGGL(deg_kernel, dim3(partBlocks), dim3(256), 0, stream, packed, cnt, E);
    hipLaunchKernelGGL(scan_partial, dim3(nbScan), dim3(1024), 0, stream, cnt, psum, n);
    hipLaunchKernelGGL(scan_base, dim3(1), dim3(64), 0, stream, psum, pbase, rowp, nbScan, n);
    hipLaunchKernelGGL(scan_final, dim3(nbScan), dim3(1024), 0, stream, cnt, pbase, rowp, dinv, col, n);

    // layer 1 GEMM (BK=32, 17KB LDS) fused with XCD-partitioned packed fill
    hipLaunchKernelGGL(gemm1_fill, dim3(gblocks + partBlocks), dim3(256), 0, stream,
                       x, Wt1, bufA, n, dinv, packed, cnt, col, E, gblocks);
    hipLaunchKernelGGL((agg_kernel<0>), dim3(ablocks), dim3(256), 0, stream,
                       bufA, rowp, col, dinv, b1, hb, stats, n);
    // layer 2
    hipLaunchKernelGGL((mfma_gemm<short, OUT_DIM, 64, true>), dim3(gblocks), dim3(256), 0, stream,
                       (const short*)hb, Wt2, bufA, n, stats, g1, be1, a1, dinv);
    hipLaunchKernelGGL((agg_kernel<0>), dim3(ablocks), dim3(256), 0, stream,
                       bufA, rowp, col, dinv, b2, hb, stats + 2048, n);
    // layer 3
    hipLaunchKernelGGL((mfma_gemm<short, OUT_DIM, 64, true>), dim3(gblocks), dim3(256), 0, stream,
                       (const short*)hb, Wt3, bufA, n, stats + 2048, g2, be2, a2, dinv);
    hipLaunchKernelGGL((agg_kernel<1>), dim3(ablocks), dim3(256), 0, stream,
                       bufA, rowp, col, dinv, b3, out, nullptr, n);
}